// Round 8
// baseline (23.730 us; speedup 1.0000x reference)
//
#include <hip/hip_runtime.h>

typedef short bf16x8 __attribute__((ext_vector_type(8)));
typedef float f32x4  __attribute__((ext_vector_type(4)));
typedef unsigned short u16;
typedef unsigned int   u32;

#define HH 128
#define WW 128

__device__ __forceinline__ u32 cvt_pk_bf16(float lo, float hi) {
    u32 r;
    asm volatile("v_cvt_pk_bf16_f32 %0, %1, %2" : "=v"(r) : "v"(lo), "v"(hi));
    return r;   // low16 = bf16(lo), high16 = bf16(hi)
}

// Implicit-GEMM conv via 9 shifted 32x32 channel GEMMs on mfma_f32_16x16x32_bf16.
// Block: 1024 thr (16 waves) owns 8 contiguous output rows of one batch.
// Wave = (row 0..7, nh 0..1): one output row, all 32 out-ch, 4 of 8 col-tiles
//   -> each B-frag ds_read_b128 feeds 2 MFMAs.
// 10 staged rows (halo 1.25x) in a flat 10-slot LDS buffer; ONE barrier
// between staging and compute; 16 waves/CU (4/SIMD) for latency hiding.
// A-frags: oh=0 resident in regs, oh=1 re-read from LDS per (lc,k) to stay
// under the 128-VGPR cap at 1 block/CU.
// Grid: 256 blocks (16 b x 16 groups), XCD-bijective swizzle, 1 block/CU.
__global__ __launch_bounds__(1024, 1) void geps_mfma_kernel(
    const float* __restrict__ x, const float* __restrict__ codes,
    const float* __restrict__ weight, const float* __restrict__ A,
    const float* __restrict__ Bm, const float* __restrict__ bias,
    const float* __restrict__ bctx, float* __restrict__ out)
{
    // [10 slots][8 col-slots][4 ig][16 p] x 8ch bf16 = 81920 B
    __shared__ bf16x8 lds_x[5120];
    // [9 kl][2 oh][4 kb][16 o] x 8i bf16 = 18432 B (A-frag = 1 linear b128)
    __shared__ bf16x8 lds_w[1152];
    __shared__ float  lds_ctx[576];   // [i][r][kl] = sum_c A[i,c,kl]*codes[c,r]
    __shared__ float  lds_b[32];

    const int tid  = threadIdx.x;
    const int l    = tid & 63;
    const int wvid = tid >> 6;         // 0..15
    const int row  = wvid >> 1;        // output row within group: 0..7
    const int nh   = wvid & 1;         // column-tile half: nt = nh*4 + 0..3

    // XCD-aware bijective swizzle: 256 blocks = 8 XCDs x 32 contiguous.
    const int orig = blockIdx.x;
    const int vb   = (orig & 7) * 32 + (orig >> 3);
    const int b    = vb >> 4;          // batch 0..15
    const int grp  = vb & 15;          // 8-row group 0..15
    const int h0   = grp * 8;          // rows h0..h0+7

    const float c00 = codes[b * 4 + 0];
    const float c01 = codes[b * 4 + 1];
    const float c10 = codes[b * 4 + 2];
    const float c11 = codes[b * 4 + 3];

    // ---- Phase 1: code contraction + per-sample bias ----
    if (tid < 576) {
        int j = tid;
        int i = j / 18, rem = j % 18, r = rem / 9, kl = rem % 9;
        float a0 = A[(i * 2 + 0) * 9 + kl];
        float a1 = A[(i * 2 + 1) * 9 + kl];
        lds_ctx[j] = (r == 0) ? (a0 * c00 + a1 * c10) : (a0 * c01 + a1 * c11);
    }
    if (tid < 32) lds_b[tid] = bias[tid] + c00 * bctx[tid] + c11 * bctx[32 + tid];
    __syncthreads();

    // ---- Phase 2a: stage x rows h0-1..h0+8 into slots 0..9 (BW-critical,
    //      issued first).  item = (rr, ig, cp, jhalf): 4 float2 loads,
    //      2 ds_write_b64 (lower/upper 8B of the two 16B entries). ----
    #pragma unroll
    for (int it = 0; it < 5; ++it) {
        int idx   = it * 1024 + tid;   // < 5120
        int jh    = idx & 1;
        int cp    = (idx >> 1) & 63;
        int ig    = (idx >> 7) & 3;
        int rr    = idx >> 9;          // 0..9
        int c0    = cp * 2;
        int grow  = (h0 - 1 + rr) & 127;
        const float* src =
            x + ((size_t)(b * 32 + ig * 8 + jh * 4) * HH + grow) * WW + c0;
        float2 f[4];
        #pragma unroll
        for (int jj = 0; jj < 4; ++jj)
            f[jj] = *(const float2*)(src + (size_t)jj * HH * WW);
        u32 w0a = cvt_pk_bf16(f[0].x, f[1].x);
        u32 w0b = cvt_pk_bf16(f[2].x, f[3].x);
        u32 w1a = cvt_pk_bf16(f[0].y, f[1].y);
        u32 w1b = cvt_pk_bf16(f[2].y, f[3].y);
        int didx = rr * 512 + (c0 >> 4) * 64 + ig * 16 + (c0 & 15);
        u32* base = (u32*)lds_x;
        *(uint2*)&base[didx * 4 + jh * 2]       = make_uint2(w0a, w0b);
        *(uint2*)&base[(didx + 1) * 4 + jh * 2] = make_uint2(w1a, w1b);
    }

    // ---- Phase 2b: synthesize combined weights -> bf16 LDS (coalesced) ----
    for (int j = tid; j < 1152; j += 1024) {
        int kl = j >> 7, rem = j & 127, o = rem >> 2, kb = rem & 3;
        float m0 = Bm[(o * 2 + 0) * 9 + kl];
        float m1 = Bm[(o * 2 + 1) * 9 + kl];
        float wf[8];
        #pragma unroll
        for (int jj = 0; jj < 8; ++jj) {
            int i = kb * 8 + jj;
            wf[jj] = weight[(o * 32 + i) * 9 + kl]
                   + lds_ctx[i * 18 + kl] * m0
                   + lds_ctx[i * 18 + 9 + kl] * m1;
        }
        u32 pk[4];
        #pragma unroll
        for (int q = 0; q < 4; ++q) pk[q] = cvt_pk_bf16(wf[2 * q], wf[2 * q + 1]);
        *(uint4*)&lds_w[kl * 128 + (o >> 4) * 64 + kb * 16 + (o & 15)] =
            make_uint4(pk[0], pk[1], pk[2], pk[3]);
    }
    __syncthreads();

    // ---- A fragments: oh=0 resident (36 VGPRs); oh=1 read in-loop ----
    const int awb = (l >> 4) * 16 + (l & 15);
    bf16x8 af0[9];
    #pragma unroll
    for (int kl = 0; kl < 9; ++kl)
        af0[kl] = lds_w[kl * 128 + awb];

    // ---- B-address bases per tap-column shift dl in {-1,0,1} ----
    const int p = l & 15, igf = l >> 4;
    int bb[3];
    #pragma unroll
    for (int dl = -1; dl <= 1; ++dl) {
        int pq = p + dl;                       // -1..16
        bb[dl + 1] = (pq & 15) + ((pq >> 4) << 6) + igf * 16;  // 16B-elem units
    }

    f32x4 acc[2][4];
    #pragma unroll
    for (int oh = 0; oh < 2; ++oh)
        #pragma unroll
        for (int q = 0; q < 4; ++q) acc[oh][q] = (f32x4){0.f, 0.f, 0.f, 0.f};

    // ---- Main loop: (lc,k) outer, q inner; each bfv feeds 2 MFMAs ----
    #pragma unroll
    for (int lc = 0; lc < 3; ++lc) {
        #pragma unroll
        for (int k = 0; k < 3; ++k) {
            const bf16x8 a0 = af0[k * 3 + lc];
            const bf16x8 a1 = lds_w[(k * 3 + lc) * 128 + 64 + awb];
            #pragma unroll
            for (int q = 0; q < 4; ++q) {
                int t = (bb[lc] + (nh * 4 + q) * 64) & 511;  // col wrap
                bf16x8 bfv = lds_x[(row + k) * 512 + t];
                acc[0][q] = __builtin_amdgcn_mfma_f32_16x16x32_bf16(
                    a0, bfv, acc[0][q], 0, 0, 0);
                acc[1][q] = __builtin_amdgcn_mfma_f32_16x16x32_bf16(
                    a1, bfv, acc[1][q], 0, 0, 0);
            }
        }
    }

    // ---- Epilogue: bias + store (D: col=lane&15 -> w, row=(lane>>4)*4+reg -> o) ----
    float blr[2][4];
    #pragma unroll
    for (int oh = 0; oh < 2; ++oh)
        #pragma unroll
        for (int r = 0; r < 4; ++r)
            blr[oh][r] = lds_b[oh * 16 + (l >> 4) * 4 + r];

    const int h = h0 + row;
    const size_t obase = ((size_t)(b * 32 + (l >> 4) * 4) * HH + h) * WW + p;
    #pragma unroll
    for (int oh = 0; oh < 2; ++oh)
        #pragma unroll
        for (int q = 0; q < 4; ++q)
            #pragma unroll
            for (int r = 0; r < 4; ++r)
                out[obase + (size_t)(oh * 16 + r) * (HH * WW) + (nh * 4 + q) * 16] =
                    acc[oh][q][r] + blr[oh][r];
}

extern "C" void kernel_launch(void* const* d_in, const int* in_sizes, int n_in,
                              void* d_out, int out_size, void* d_ws, size_t ws_size,
                              hipStream_t stream) {
    const float* x      = (const float*)d_in[0];
    const float* codes  = (const float*)d_in[1];
    const float* weight = (const float*)d_in[2];
    const float* A      = (const float*)d_in[3];
    const float* Bm     = (const float*)d_in[4];
    const float* bias   = (const float*)d_in[5];
    const float* bctx   = (const float*)d_in[6];
    float* out = (float*)d_out;

    hipLaunchKernelGGL(geps_mfma_kernel, dim3(256), dim3(1024), 0, stream,
                       x, codes, weight, A, Bm, bias, bctx, out);
}